// Round 2
// baseline (897.214 us; speedup 1.0000x reference)
//
#include <hip/hip_runtime.h>
#include <hip/hip_bf16.h>
#include <cstdint>
#include <cstddef>

#define D_MODEL 512
#define HIDDEN  2048
#define N_EXP   8
#define NTOK    8192          // 4 * 2048 tokens
#define MAXROWS (NTOK * 2)

typedef unsigned short u16;
typedef _Float16 half8 __attribute__((ext_vector_type(8)));
typedef float   f32x16 __attribute__((ext_vector_type(16)));

// ---------------------------------------------------------------------------
// helpers: fp16 hi/lo split packing
// ---------------------------------------------------------------------------
__device__ __forceinline__ unsigned pk2(_Float16 a, _Float16 b) {
    unsigned short ua, ub;
    __builtin_memcpy(&ua, &a, 2); __builtin_memcpy(&ub, &b, 2);
    return (unsigned)ua | ((unsigned)ub << 16);
}
__device__ __forceinline__ void split2(float a, float b, unsigned& h, unsigned& l) {
    _Float16 ha = (_Float16)a, hb = (_Float16)b;      // RNE
    float ra = a - (float)ha, rb = b - (float)hb;     // residuals
    h = pk2(ha, hb);
    l = pk2((_Float16)ra, (_Float16)rb);
}
__device__ __forceinline__ half8 h8(uint2 lo, uint2 hi) {
    union { unsigned u[4]; half8 h; } t;
    t.u[0] = lo.x; t.u[1] = lo.y; t.u[2] = hi.x; t.u[3] = hi.y;
    return t.h;
}
__device__ __forceinline__ f32x16 mfma16(half8 a, half8 b, f32x16 c) {
    return __builtin_amdgcn_mfma_f32_32x32x16_f16(a, b, c, 0, 0, 0);
}
__device__ __forceinline__ void gload16(const void* g, void* l) {
    __builtin_amdgcn_global_load_lds(
        (const __attribute__((address_space(1))) unsigned int*)g,
        (__attribute__((address_space(3))) unsigned int*)l, 16, 0, 0);
}

// ---------------------------------------------------------------------------
// Gate: one 64-lane wave per token. scores = x . Wg + bg ; top-2 ; softmax.
// ---------------------------------------------------------------------------
__global__ __launch_bounds__(256) void gate_kernel(
    const float* __restrict__ x, const float* __restrict__ Wg,
    const float* __restrict__ bg,
    int* __restrict__ eidx, float* __restrict__ ewt, int* __restrict__ cnt)
{
    const int wid  = threadIdx.x >> 6;
    const int lane = threadIdx.x & 63;
    const int t = blockIdx.x * 4 + wid;
    const float* xr = x + (size_t)t * D_MODEL;

    float p[8] = {0.f,0.f,0.f,0.f,0.f,0.f,0.f,0.f};
    for (int i = lane; i < D_MODEL; i += 64) {
        const float xv = xr[i];
        const float4 a = *(const float4*)(Wg + (size_t)i * 8);
        const float4 b = *(const float4*)(Wg + (size_t)i * 8 + 4);
        p[0] += xv*a.x; p[1] += xv*a.y; p[2] += xv*a.z; p[3] += xv*a.w;
        p[4] += xv*b.x; p[5] += xv*b.y; p[6] += xv*b.z; p[7] += xv*b.w;
    }
    #pragma unroll
    for (int off = 32; off >= 1; off >>= 1) {
        #pragma unroll
        for (int e = 0; e < 8; ++e) p[e] += __shfl_xor(p[e], off, 64);
    }
    if (lane == 0) {
        float s[8];
        #pragma unroll
        for (int e = 0; e < 8; ++e) s[e] = p[e] + bg[e];
        int e1 = 0; float v1 = s[0];
        #pragma unroll
        for (int e = 1; e < 8; ++e) if (s[e] > v1) { v1 = s[e]; e1 = e; }
        int e2 = -1; float v2 = -3.0e38f;
        #pragma unroll
        for (int e = 0; e < 8; ++e) if (e != e1 && s[e] > v2) { v2 = s[e]; e2 = e; }
        const float w1 = 1.f / (1.f + expf(v2 - v1));
        eidx[2*t]   = e1;  eidx[2*t+1] = e2;
        ewt [2*t]   = w1;  ewt [2*t+1] = 1.f - w1;
        atomicAdd(&cnt[e1], 1);
        atomicAdd(&cnt[e2], 1);
    }
}

__global__ void scan_kernel(const int* __restrict__ cnt,
                            int* __restrict__ offs, int* __restrict__ cur)
{
    if (threadIdx.x == 0) {
        int run = 0;
        #pragma unroll
        for (int e = 0; e < 8; ++e) { offs[e] = run; cur[e] = run; run += cnt[e]; }
    }
}

__global__ __launch_bounds__(256) void route_kernel(
    const int* __restrict__ eidx, const float* __restrict__ ewt,
    int* __restrict__ cur, int* __restrict__ rows, float* __restrict__ rwt)
{
    const int t = blockIdx.x * 256 + threadIdx.x;
    if (t >= NTOK) return;
    #pragma unroll
    for (int k = 0; k < 2; ++k) {
        const int e = eidx[2*t + k];
        const int pos = atomicAdd(&cur[e], 1);
        rows[pos] = t;
        rwt [pos] = ewt[2*t + k];
    }
}

// ---------------------------------------------------------------------------
// Prologue: split W1 (as W1^T) into fp16 h/l planes, laid out as the exact
// 32KB LDS pieces the main kernel stages:  [e][hc4][ds4][pa8] x
// piece {pl2}{dcb2}{h512}{dj8}  (k-slot = pa*16 + dcb*8 + dj, dcb==lane-group)
// ---------------------------------------------------------------------------
__global__ __launch_bounds__(256) void conv_w1(const float* __restrict__ W1,
                                               u16* __restrict__ W1c)
{
    const int e = blockIdx.z;
    const int h0 = blockIdx.x * 64, d0 = blockIdx.y * 64;
    __shared__ float T[64][65];
    const int hl = threadIdx.x & 63, q = threadIdx.x >> 6;
    const float* src = W1 + (size_t)e * D_MODEL * HIDDEN;
    #pragma unroll
    for (int rr = 0; rr < 16; ++rr) {
        const int d = rr*4 + q;
        T[d][hl] = src[(size_t)(d0 + d) * HIDDEN + h0 + hl];
    }
    __syncthreads();
    #pragma unroll
    for (int it = 0; it < 2; ++it) {
        const int dblk = q + 4*it;
        float v[8];
        #pragma unroll
        for (int j = 0; j < 8; ++j) v[j] = T[dblk*8 + j][hl];
        unsigned hh[4], ll[4];
        #pragma unroll
        for (int p = 0; p < 4; ++p) split2(v[2*p], v[2*p+1], hh[p], ll[p]);
        const int gd = d0 + dblk*8, gh = h0 + hl;
        const int hc = gh >> 9, hloc = gh & 511;
        const int ds = gd >> 7, pa = (gd >> 4) & 7, dcb = (gd >> 3) & 1;
        u16* dst = W1c + ((size_t)(((e*4 + hc)*4 + ds)*8 + pa))*16384
                       + dcb*4096 + hloc*8;
        *(uint4*)dst          = make_uint4(hh[0], hh[1], hh[2], hh[3]);
        *(uint4*)(dst + 8192) = make_uint4(ll[0], ll[1], ll[2], ll[3]);
    }
}

// W2 (as W2^T): pieces [e][hc4][pb32] x {pl2}{hb4}{d512}{hi4}
// k-slot = pb*16 + hb*4 + hi ; frag elems j0..3 at hb=g, j4..7 at hb=g+2
// ---------------------------------------------------------------------------
__global__ __launch_bounds__(256) void conv_w2(const float* __restrict__ W2,
                                               u16* __restrict__ W2c)
{
    const int e = blockIdx.z;
    const int h0 = blockIdx.x * 64, d0 = blockIdx.y * 64;
    __shared__ float T[64][65];
    const int c63 = threadIdx.x & 63, q = threadIdx.x >> 6;
    const float* src = W2 + (size_t)e * HIDDEN * D_MODEL;
    #pragma unroll
    for (int rr = 0; rr < 16; ++rr) {
        const int h = rr*4 + q;
        T[h][c63] = src[(size_t)(h0 + h) * D_MODEL + d0 + c63];
    }
    __syncthreads();
    #pragma unroll
    for (int it = 0; it < 2; ++it) {
        const int cc = it*256 + threadIdx.x;
        const int hbl = cc >> 5, dp = cc & 31;
        unsigned hh[4], ll[4];
        #pragma unroll
        for (int dd = 0; dd < 2; ++dd) {
            split2(T[hbl*4+0][dp*2+dd], T[hbl*4+1][dp*2+dd], hh[dd*2+0], ll[dd*2+0]);
            split2(T[hbl*4+2][dp*2+dd], T[hbl*4+3][dp*2+dd], hh[dd*2+1], ll[dd*2+1]);
        }
        const int gh = h0 + hbl*4, gd = d0 + dp*2;
        const int hc = gh >> 9, pb = (gh >> 4) & 31, hb = (gh >> 2) & 3;
        u16* dst = W2c + ((size_t)((e*4 + hc)*32 + pb))*16384 + hb*2048 + gd*4;
        *(uint4*)dst          = make_uint4(hh[0], hh[1], hh[2], hh[3]);
        *(uint4*)(dst + 8192) = make_uint4(ll[0], ll[1], ll[2], ll[3]);
    }
}

// ---------------------------------------------------------------------------
// Fused MoE expert kernel (fast path). Block = (expert, 64 routed tokens),
// 512 threads (8 waves). Transposed compute with 32x32x16 f16 MFMA, fp16
// hi/lo 3-term split. D1[h][tok] = W1^T x^T  (H stays in registers),
// D2[d][tok] += W2^T H  (H exchanged wave->wave via 4KB LDS pieces).
// One global_load_lds-staged 32KB weight piece per MFMA k-step, double-
// buffered, one __syncthreads per phase.
// ---------------------------------------------------------------------------
__global__ __launch_bounds__(512, 2) void moe_mfma(
    const float* __restrict__ x,
    const u16* __restrict__ W1c, const u16* __restrict__ W2c,
    const float* __restrict__ b1, const float* __restrict__ b2,
    const int* __restrict__ cnt, const int* __restrict__ offs,
    const int* __restrict__ rows, const float* __restrict__ rwt,
    float* __restrict__ out)
{
    const int e  = blockIdx.y;
    const int n  = cnt[e];
    const int t0 = blockIdx.x * 64;
    if (t0 >= n) return;
    const int base   = offs[e];
    const int mcount = min(64, n - t0);

    const int tid  = threadIdx.x;
    const int wv   = tid >> 6;        // 0..7
    const int lane = tid & 63;
    const int g    = lane >> 5;       // 0/1 lane-group
    const int l31  = lane & 31;

    __shared__ __align__(16) u16  Wp[2][16384];          // 64 KB weight piece dbuf
    __shared__ __align__(16) u16  Xs[2][16][64][8];      // 32 KB X slab (pl,dc,tok,dj)
    __shared__ __align__(16) u16  Hp[2][2][4][64][4];    // 8 KB H piece dbuf (buf,pl,hb,tok,hi)
    __shared__ float b1s[512];
    __shared__ int   toks_s[64];
    __shared__ float wts_s[64];

    if (tid < 64) {
        int tk = 0; float ww = 0.f;
        if (tid < mcount) { tk = rows[base + t0 + tid]; ww = rwt[base + t0 + tid]; }
        toks_s[tid] = tk; wts_s[tid] = ww;
    }
    __syncthreads();

    const float* b1e = b1 + (size_t)e * HIDDEN;

    auto w1p = [&](int hc, int ds, int pa) {
        return W1c + ((size_t)(((e*4 + hc)*4 + ds)*8 + pa)) * 16384;
    };
    auto w2p = [&](int hc, int pb) {
        return W2c + ((size_t)((e*4 + hc)*32 + pb)) * 16384;
    };
    auto stageW = [&](const u16* src, int buf) {
        const char* s = (const char*)src;
        char* d = (char*)&Wp[buf][0];
        #pragma unroll
        for (int k = 0; k < 4; ++k) {
            const int off = (k*8 + wv) * 1024;      // wave-uniform LDS dest
            gload16(s + off + lane*16, d + off);    // per-lane global src
        }
    };
    auto stageX = [&](int ds) {   // reg-staged + converted; wave wv does d-cols [wv*16, wv*16+16)
        const float* xr = x + (size_t)toks_s[lane] * D_MODEL + ds*128 + wv*16;
        const float4 v0 = *(const float4*)(xr + 0), v1 = *(const float4*)(xr + 4);
        const float4 v2 = *(const float4*)(xr + 8), v3 = *(const float4*)(xr + 12);
        unsigned h[4], l[4];
        split2(v0.x, v0.y, h[0], l[0]); split2(v0.z, v0.w, h[1], l[1]);
        split2(v1.x, v1.y, h[2], l[2]); split2(v1.z, v1.w, h[3], l[3]);
        *(uint4*)&Xs[0][wv*2][lane][0]   = make_uint4(h[0], h[1], h[2], h[3]);
        *(uint4*)&Xs[1][wv*2][lane][0]   = make_uint4(l[0], l[1], l[2], l[3]);
        split2(v2.x, v2.y, h[0], l[0]); split2(v2.z, v2.w, h[1], l[1]);
        split2(v3.x, v3.y, h[2], l[2]); split2(v3.z, v3.w, h[3], l[3]);
        *(uint4*)&Xs[0][wv*2+1][lane][0] = make_uint4(h[0], h[1], h[2], h[3]);
        *(uint4*)&Xs[1][wv*2+1][lane][0] = make_uint4(l[0], l[1], l[2], l[3]);
    };

    f32x16 d1[2][2], d2[2][2];
    #pragma unroll
    for (int a = 0; a < 2; ++a)
        #pragma unroll
        for (int b = 0; b < 2; ++b)
            #pragma unroll
            for (int r = 0; r < 16; ++r) d2[a][b][r] = 0.f;

    unsigned hpk[2][2][2][2][4];   // [mfs][c][tf][pl][q] — literal-indexed only

    auto writeH = [&](u16* hp, const unsigned (&hk)[2][2][4]) {
        #pragma unroll
        for (int tf = 0; tf < 2; ++tf)
            #pragma unroll
            for (int pl = 0; pl < 2; ++pl) {
                *(uint2*)&hp[((pl*4 + g    )*64 + tf*32 + l31)*4] = make_uint2(hk[tf][pl][0], hk[tf][pl][1]);
                *(uint2*)&hp[((pl*4 + g + 2)*64 + tf*32 + l31)*4] = make_uint2(hk[tf][pl][2], hk[tf][pl][3]);
            }
    };
    auto ownerH = [&](int pn) {   // write H piece pn into Hp[pn&1]
        const int f = pn >> 1;                 // h-frag = owner info
        if (wv != (f >> 1)) return;            // wave w owns frags {2w, 2w+1}
        u16* hp = &Hp[pn & 1][0][0][0][0];
        if (f & 1) { if (pn & 1) writeH(hp, hpk[1][1]); else writeH(hp, hpk[1][0]); }
        else       { if (pn & 1) writeH(hp, hpk[0][1]); else writeH(hp, hpk[0][0]); }
    };

    auto computeA = [&](int cur, int pa) {
        const u16* wp = &Wp[cur][0];
        half8 aw[2][2], bx[2][2];
        #pragma unroll
        for (int mfs = 0; mfs < 2; ++mfs)
            #pragma unroll
            for (int pl = 0; pl < 2; ++pl)
                aw[mfs][pl] = *(const half8*)&wp[pl*8192 + g*4096 + ((2*wv + mfs)*32 + l31)*8];
        #pragma unroll
        for (int tf = 0; tf < 2; ++tf)
            #pragma unroll
            for (int pl = 0; pl < 2; ++pl)
                bx[tf][pl] = *(const half8*)&Xs[pl][2*pa + g][tf*32 + l31][0];
        #pragma unroll
        for (int mfs = 0; mfs < 2; ++mfs)
            #pragma unroll
            for (int tf = 0; tf < 2; ++tf) {
                d1[mfs][tf] = mfma16(aw[mfs][0], bx[tf][0], d1[mfs][tf]);
                d1[mfs][tf] = mfma16(aw[mfs][0], bx[tf][1], d1[mfs][tf]);
                d1[mfs][tf] = mfma16(aw[mfs][1], bx[tf][0], d1[mfs][tf]);
            }
    };
    auto computeB = [&](int cur, int pb) {
        const u16* wp = &Wp[cur][0];
        const u16* hp = &Hp[pb & 1][0][0][0][0];
        half8 aw[2][2], bh[2][2];
        #pragma unroll
        for (int mfs = 0; mfs < 2; ++mfs)
            #pragma unroll
            for (int pl = 0; pl < 2; ++pl) {
                const int d = (2*wv + mfs)*32 + l31;
                uint2 lo = *(const uint2*)&wp[pl*8192 + (g    )*2048 + d*4];
                uint2 hi = *(const uint2*)&wp[pl*8192 + (g + 2)*2048 + d*4];
                aw[mfs][pl] = h8(lo, hi);
            }
        #pragma unroll
        for (int tf = 0; tf < 2; ++tf)
            #pragma unroll
            for (int pl = 0; pl < 2; ++pl) {
                uint2 lo = *(const uint2*)&hp[((pl*4 + g    )*64 + tf*32 + l31)*4];
                uint2 hi = *(const uint2*)&hp[((pl*4 + g + 2)*64 + tf*32 + l31)*4];
                bh[tf][pl] = h8(lo, hi);
            }
        #pragma unroll
        for (int mfs = 0; mfs < 2; ++mfs)
            #pragma unroll
            for (int tf = 0; tf < 2; ++tf) {
                d2[mfs][tf] = mfma16(aw[mfs][0], bh[tf][0], d2[mfs][tf]);
                d2[mfs][tf] = mfma16(aw[mfs][0], bh[tf][1], d2[mfs][tf]);
                d2[mfs][tf] = mfma16(aw[mfs][1], bh[tf][0], d2[mfs][tf]);
            }
    };
    auto finishH = [&]() {
        #pragma unroll
        for (int mfs = 0; mfs < 2; ++mfs) {
            const int hbase = (2*wv + mfs) * 32;
            #pragma unroll
            for (int tf = 0; tf < 2; ++tf) {
                const float wt = wts_s[tf*32 + l31];
                float t[16];
                #pragma unroll
                for (int r = 0; r < 16; ++r) {
                    const int ho = (r & 3) + 8*(r >> 2) + 4*g;   // verified C/D row map
                    t[r] = fmaxf(d1[mfs][tf][r] + b1s[hbase + ho], 0.f) * wt;
                }
                #pragma unroll
                for (int c = 0; c < 2; ++c)
                    #pragma unroll
                    for (int q = 0; q < 4; ++q)
                        split2(t[8*c + 2*q], t[8*c + 2*q + 1],
                               hpk[mfs][c][tf][0][q], hpk[mfs][c][tf][1][q]);
            }
        }
    };

    // prologue staging
    stageX(0);
    stageW(w1p(0, 0, 0), 0);
    int cur = 0;
    __syncthreads();   // drains gload_lds (vmcnt0 at barrier) + Xs writes

    #pragma unroll 1
    for (int hc = 0; hc < 4; ++hc) {
        b1s[tid] = b1e[hc*512 + tid];
        #pragma unroll
        for (int a = 0; a < 2; ++a)
            #pragma unroll
            for (int b = 0; b < 2; ++b)
                #pragma unroll
                for (int r = 0; r < 16; ++r) d1[a][b][r] = 0.f;

        // ---- Phase A: D1 = W1^T X^T over d=512 (4 slabs x 8 pieces) ----
        #pragma unroll 1
        for (int ds = 0; ds < 4; ++ds) {
            #pragma unroll 2
            for (int pa = 0; pa < 8; ++pa) {
                if (pa < 7)      stageW(w1p(hc, ds, pa + 1), cur ^ 1);
                else if (ds < 3) stageW(w1p(hc, ds + 1, 0),  cur ^ 1);
                else             stageW(w2p(hc, 0),          cur ^ 1);
                computeA(cur, pa);
                if (pa == 7 && ds < 3) stageX(ds + 1);
                __syncthreads();
                cur ^= 1;
            }
        }

        // ---- H: bias+relu+gate-scale, fp16 split, in registers ----
        finishH();
        ownerH(0);
        __syncthreads();

        // ---- Phase B: D2 += W2^T H over h=512 (32 pieces) ----
        #pragma unroll 2
        for (int pb = 0; pb < 32; ++pb) {
            if (pb < 31)     stageW(w2p(hc, pb + 1),    cur ^ 1);
            else if (hc < 3) stageW(w1p(hc + 1, 0, 0),  cur ^ 1);
            if (pb < 31) ownerH(pb + 1);
            computeB(cur, pb);
            if (pb == 31 && hc < 3) stageX(0);
            __syncthreads();
            cur ^= 1;
        }
    }

    // ---- epilogue: transpose D2[d][tok] via LDS, coalesced atomicAdd ----
    float* Ot = (float*)&Wp[0][0];   // [64][129] f32, reuses weight-piece LDS
    const float* b2e = b2 + (size_t)e * D_MODEL;
    #pragma unroll 1
    for (int c = 0; c < 4; ++c) {
        if ((wv >> 1) == c) {
            #pragma unroll
            for (int mfs = 0; mfs < 2; ++mfs)
                #pragma unroll
                for (int tf = 0; tf < 2; ++tf)
                    #pragma unroll
                    for (int r = 0; r < 16; ++r) {
                        const int dl = (wv & 1)*64 + mfs*32 + (r & 3) + 8*(r >> 2) + 4*g;
                        Ot[(tf*32 + l31)*129 + dl] = d2[mfs][tf][r];
                    }
        }
        __syncthreads();
        #pragma unroll
        for (int it = 0; it < 16; ++it) {
            const int flat = it*512 + tid;
            const int tk = flat >> 7, dl = flat & 127;
            if (tk < mcount)
                atomicAdd(out + (size_t)toks_s[tk]*D_MODEL + c*128 + dl,
                          Ot[tk*129 + dl] + wts_s[tk]*b2e[c*128 + dl]);
        }
        __syncthreads();
    }
}

// ---------------------------------------------------------------------------
// Fallback fp32 expert kernel (used only if ws_size is too small for the
// converted-weight planes). Same structure as round-0.
// ---------------------------------------------------------------------------
__global__ __launch_bounds__(512) void moe_fp32(
    const float* __restrict__ x,
    const float* __restrict__ W1, const float* __restrict__ b1,
    const float* __restrict__ W2, const float* __restrict__ b2,
    const int* __restrict__ cnt, const int* __restrict__ offs,
    const int* __restrict__ rows, const float* __restrict__ rwt,
    float* __restrict__ out)
{
    const int e  = blockIdx.y;
    const int n  = cnt[e];
    const int t0 = blockIdx.x * 32;
    if (t0 >= n) return;
    const int base   = offs[e];
    const int mcount = min(32, n - t0);

    __shared__ float Xs[32 * 512];
    __shared__ float Ws[32 * 512];
    __shared__ float Hs[32 * 36];
    __shared__ int   toks[32];
    __shared__ float wts[32];

    const int tid  = threadIdx.x;
    const int w    = tid >> 6;
    const int lane = tid & 63;

    if (tid < 32) {
        int tk = 0; float ww = 0.f;
        if (tid < mcount) { tk = rows[base + t0 + tid]; ww = rwt[base + t0 + tid]; }
        toks[tid] = tk; wts[tid] = ww;
    }
    __syncthreads();

    float4* Xs4 = (float4*)Xs;
    for (int i = tid; i < 32 * 128; i += 512) {
        const int m = i >> 7, c4 = i & 127;
        float4 v = make_float4(0.f, 0.f, 0.f, 0.f);
        if (m < mcount) v = *(const float4*)(x + (size_t)toks[m] * D_MODEL + c4 * 4);
        Xs4[m * 128 + (c4 ^ (m & 7))] = v;
    }

    const int mA = (lane & 15) | ((w & 1) << 4);
    const int hA = ((w >> 1) << 3) | ((lane >> 4) << 1);
    const int sx = mA & 7;
    const int s0 = (hA >> 2) & 7;
    const int mB = (w & 1) << 4;
    const int dB = ((w >> 1) << 7) + lane * 2;

    float2 acc[16];
    #pragma unroll
    for (int mi = 0; mi < 16; ++mi) acc[mi] = make_float2(0.f, 0.f);

    const float* W1e = W1 + (size_t)e * (D_MODEL * HIDDEN);
    const float* W2e = W2 + (size_t)e * (HIDDEN * D_MODEL);
    const float* b1e = b1 + (size_t)e * HIDDEN;

    const int hq     = tid & 7;
    const int dstage = tid >> 3;
    float4* Ws4 = (float4*)Ws;

    for (int hcc = 0; hcc < HIDDEN / 32; ++hcc) {
        const int h0 = hcc * 32;
        {
            const float* src = W1e + h0 + hq * 4;
            #pragma unroll
            for (int pp = 0; pp < 8; ++pp) {
                const int d = pp * 64 + dstage;
                const float4 v = *(const float4*)(src + (size_t)d * HIDDEN);
                const int dsz = d ^ (hq << 2);
                Ws[(hq * 4 + 0) * 512 + dsz] = v.x;
                Ws[(hq * 4 + 1) * 512 + dsz] = v.y;
                Ws[(hq * 4 + 2) * 512 + dsz] = v.z;
                Ws[(hq * 4 + 3) * 512 + dsz] = v.w;
            }
        }
        __syncthreads();
        {
            const float4* Xr  = Xs4 + mA * 128;
            const float4* Wr0 = Ws4 + hA * 128;
            const float4* Wr1 = Ws4 + (hA + 1) * 128;
            float4 A0 = make_float4(0,0,0,0), A1 = make_float4(0,0,0,0);
            #pragma unroll 4
            for (int d4 = 0; d4 < 128; ++d4) {
                const float4 xv = Xr[d4 ^ sx];
                const float4 u  = Wr0[d4 ^ s0];
                const float4 vv = Wr1[d4 ^ s0];
                A0.x += xv.x*u.x;  A0.y += xv.y*u.y;  A0.z += xv.z*u.z;  A0.w += xv.w*u.w;
                A1.x += xv.x*vv.x; A1.y += xv.y*vv.y; A1.z += xv.z*vv.z; A1.w += xv.w*vv.w;
            }
            const float a0 = (A0.x + A0.y) + (A0.z + A0.w);
            const float a1 = (A1.x + A1.y) + (A1.z + A1.w);
            const float ww = wts[mA];
            Hs[mA * 36 + hA]     = fmaxf(a0 + b1e[h0 + hA],     0.f) * ww;
            Hs[mA * 36 + hA + 1] = fmaxf(a1 + b1e[h0 + hA + 1], 0.f) * ww;
        }
        __syncthreads();
        {
            const float* w2ptr = W2e + (size_t)h0 * D_MODEL + dB;
            #pragma unroll
            for (int qq = 0; qq < 8; ++qq) {
                const float2 wv0 = *(const float2*)(w2ptr + (size_t)(qq*4 + 0) * D_MODEL);
                const float2 wv1 = *(const float2*)(w2ptr + (size_t)(qq*4 + 1) * D_MODEL);
                const float2 wv2 = *(const float2*)(w2ptr + (size_t)(qq*4 + 2) * D_MODEL);
                const float2 wv3 = *(const float2*)(w2ptr + (size_t)(qq*4 + 3) * D_MODEL);
                #pragma unroll
                for (int mi = 0; mi < 16; ++mi) {
                    const float4 hv = *(const float4*)&Hs[(mB + mi) * 36 + qq * 4];
                    acc[mi].x += hv.x*wv0.x + hv.y*wv1.x + hv.z*wv2.x + hv.w*wv3.x;
                    acc[mi].y += hv.x*wv0.y + hv.y*wv1.y + hv.z*wv2.y + hv.w*wv3.y;
                }
            }
        }
    }

    const float2 b2v = *(const float2*)(b2 + (size_t)e * D_MODEL + dB);
    #pragma unroll
    for (int mi = 0; mi < 16; ++mi) {
        const int m = mB + mi;
        if (m < mcount) {
            const float ww = wts[m];
            float* op = out + (size_t)toks[m] * D_MODEL + dB;
            atomicAdd(op,     acc[mi].x + ww * b2v.x);
            atomicAdd(op + 1, acc[mi].y + ww * b2v.y);
        }
    }
}

// ---------------------------------------------------------------------------
extern "C" void kernel_launch(void* const* d_in, const int* in_sizes, int n_in,
                              void* d_out, int out_size, void* d_ws, size_t ws_size,
                              hipStream_t stream)
{
    const float* x  = (const float*)d_in[0];
    const float* W1 = (const float*)d_in[1];
    const float* b1 = (const float*)d_in[2];
    const float* W2 = (const float*)d_in[3];
    const float* b2 = (const float*)d_in[4];
    const float* Wg = (const float*)d_in[5];
    const float* bg = (const float*)d_in[6];
    float* out = (float*)d_out;

    const size_t WC_BYTES = (size_t)1024 * 32768;           // 33,554,432 each
    const size_t NEED = 2 * WC_BYTES + (1u << 20);
    const bool fast = (ws_size >= NEED);

    char* wsc = (char*)d_ws;
    u16* W1c = (u16*)wsc;
    u16* W2c = (u16*)(wsc + WC_BYTES);
    char* rbase = fast ? (wsc + 2 * WC_BYTES) : wsc;

    int*   cnt  = (int*)rbase;
    int*   offs = cnt + 8;
    int*   curp = offs + 8;
    int*   eidx = curp + 8;
    float* ewt  = (float*)(eidx + 2 * NTOK);
    int*   rows = (int*)(ewt + 2 * NTOK);
    float* rwt  = (float*)(rows + MAXROWS);

    hipMemsetAsync(cnt, 0, 24 * sizeof(int), stream);
    hipMemsetAsync(d_out, 0, (size_t)out_size * sizeof(float), stream);

    gate_kernel <<<NTOK / 4,   256, 0, stream>>>(x, Wg, bg, eidx, ewt, cnt);
    scan_kernel <<<1,          64,  0, stream>>>(cnt, offs, curp);
    route_kernel<<<NTOK / 256, 256, 0, stream>>>(eidx, ewt, curp, rows, rwt);

    if (fast) {
        conv_w1<<<dim3(32, 8, 8), 256, 0, stream>>>(W1, W1c);
        conv_w2<<<dim3(32, 8, 8), 256, 0, stream>>>(W2, W2c);
        moe_mfma<<<dim3(128, 8), 512, 0, stream>>>(x, W1c, W2c, b1, b2,
                                                   cnt, offs, rows, rwt, out);
    } else {
        moe_fp32<<<dim3(512, 8), 512, 0, stream>>>(x, W1, b1, W2, b2,
                                                   cnt, offs, rows, rwt, out);
    }
}